// Round 6
// baseline (1097.968 us; speedup 1.0000x reference)
//
#include <hip/hip_runtime.h>

// R14: attack the flat ~1.1TB/s latency wall seen by every kernel:
// (a) __builtin_nontemporal_store on all streaming epilogue stores (attn O,
//     QKV q/k/vT): stop write-allocating 32-96MB streams in the 4MB per-XCD
//     L2, which was evicting the K/V (attn) / operand (GEMM) lines and
//     forcing L3/HBM-latency reloads (R12/R13: WRITE 248->263MB unchanged by
//     store coalescing -> amplification is L2 churn, not store pattern).
// (b) attn ring depth 2->3 chunks (96KB + 17KB Ps = 133KB LDS, still 1
//     block/CU), counted vmcnt(8), in-place slot refill after the post-MFMA
//     barrier: 50% more latency cover if (a) alone is insufficient.
// Everything else identical to R13.

typedef short s8v __attribute__((ext_vector_type(8)));   // 8 bf16 = 4 VGPRs
typedef float f4v __attribute__((ext_vector_type(4)));
typedef unsigned short us;
typedef us us4v __attribute__((ext_vector_type(4)));

__device__ inline us f2b(float f) {  // fp32 -> bf16 RNE
  union { float f; unsigned u; } v; v.f = f;
  unsigned r = v.u + 0x7FFFu + ((v.u >> 16) & 1u);
  return (us)(r >> 16);
}

// async global->LDS, 16 B per lane; LDS dest = wave-uniform base + lane*16.
__device__ inline void gld16(const us* g, us* l) {
  __builtin_amdgcn_global_load_lds(
      (const __attribute__((address_space(1))) void*)g,
      (__attribute__((address_space(3))) void*)l, 16, 0, 0);
}

// ---------------------------------------------------------------------------
// Fused attention: O[zh] = softmax(alpha * Q K^T) V, streamed over KV-tiles.
// Q,K: [zh][S][E] bf16. Vt: [zh][E][S] bf16 (V^T). O: [b][S][HC*E] bf16.
// Per block: one zh, 128 q-rows. Wave w owns q-rows [q0+16w, q0+16w+16).
// KV-tile = 128 kv rows; 8 chunk-phases/tile through a 3-slot x 32KB ring:
//   ph 0-3: QK^T E-chunks (B=K-chunk), A = resident Q frags -> accS
//   (softmax-lite: exp, P'->LDS (wave-private), l += rowsum, P' frags -> pa)
//   ph 4-7: PV E-chunks (B=V^T-chunk), A = pa -> accO[ec]
// Counted s_waitcnt vmcnt(8): chunks g+1,g+2 stay in flight across barriers.
// Epilogue: nontemporal 512B-contiguous stores via wave-private LDS staging.
// ---------------------------------------------------------------------------
__global__ __launch_bounds__(512, 2) void attn_fused(
    const us* __restrict__ Q, const us* __restrict__ Kh,
    const us* __restrict__ Vt, us* __restrict__ O,
    int Lh, float alpha) {
  constexpr int S = 2048, E = 512;
  constexpr int NCH = (S / 128) * 8;  // 128 chunks total
  // Carve: ring slots 0..2 = smem[0..49152) us; Ps = smem[49152 + w*2176].
  // Epilogue reuses smem[0..34304) as wave-private O staging.
  __shared__ __align__(16) us smem[66560];  // 133,120 B
  const int t = threadIdx.x, w = t >> 6, ln = t & 63;
  const int m16 = ln & 15, quad = ln >> 4;

  // XCD swizzle: grid (16 qt, BHC zh); flat = qt + 16*zh. Remap so each XCD
  // owns consecutive nid = all qt of a few zh -> K/V L2-resident per XCD.
  const int gx = gridDim.x;  // 16
  const int nblk = gx * gridDim.y;
  const int flat = blockIdx.x + gx * blockIdx.y;
  int nid = flat;
  if ((nblk & 7) == 0) nid = (flat & 7) * (nblk >> 3) + (flat >> 3);
  const int qt = nid % gx, zh = nid / gx;

  const long long zoff = (long long)zh * S * E;
  const us* Qz = Q + zoff;
  const us* Kz = Kh + zoff;
  const us* Vz = Vt + zoff;
  const int q0 = qt * 128;

  // Resident Q fragments: lane ln holds Q[q0+16w+(ln&15)][kq*32+(ln>>4)*8 ..+7]
  s8v Qf[16];
  {
    const us* qrow = Qz + (long long)(q0 + 16 * w + m16) * E + quad * 8;
#pragma unroll
    for (int kq = 0; kq < 16; ++kq) Qf[kq] = *(const s8v*)(qrow + kq * 32);
  }

  f4v accO[4][8];
#pragma unroll
  for (int e = 0; e < 4; ++e)
#pragma unroll
    for (int nb = 0; nb < 8; ++nb) accO[e][nb] = (f4v){0.f, 0.f, 0.f, 0.f};
  float la[4] = {0.f, 0.f, 0.f, 0.f};

  // Stage chunk g into ring slot sl. Chunk: tau=g>>3, sub=g&7; sub<4 ->
  // K-chunk (kv 128 x E-slice 128, ec=sub), else V-chunk (E-slice x kv).
#define STAGE(g_, sl_)                                                       \
  {                                                                          \
    const int tau_ = (g_) >> 3, sub_ = (g_) & 7;                             \
    us* dst_ = smem + (sl_) * 16384;                                         \
    _Pragma("unroll") for (int j = 0; j < 4; ++j) {                          \
      const int c_ = t + 512 * j;                                            \
      const int s_ = c_ >> 6, l_ = c_ & 63;                                  \
      const int nbm_ = ((s_ >> 2) * 16 + (l_ & 15));                         \
      const int kk_ = (s_ & 3) * 32 + (l_ >> 4) * 8;                         \
      const us* src_ = (sub_ < 4)                                            \
          ? Kz + (long long)(tau_ * 128 + nbm_) * E + sub_ * 128 + kk_       \
          : Vz + (long long)((sub_ - 4) * 128 + nbm_) * S + tau_ * 128 + kk_;\
      gld16(src_, dst_ + c_ * 8);                                            \
    }                                                                        \
  }

  STAGE(0, 0);
  STAGE(1, 1);
  STAGE(2, 2);
  int sl = 0;  // ring slot of the current chunk (uniform, SALU)

  for (int tau = 0; tau < S / 128; ++tau) {
    f4v accS[8];
#pragma unroll
    for (int nb = 0; nb < 8; ++nb) accS[nb] = (f4v){0.f, 0.f, 0.f, 0.f};
    s8v pa[4];
#pragma unroll
    for (int ph = 0; ph < 8; ++ph) {
      const int g = tau * 8 + ph;
      const int slc = sl;
      // wait until chunk g landed; keep g+1,g+2 (8 loads) in flight
      if (g + 3 <= NCH)      asm volatile("s_waitcnt vmcnt(8)" ::: "memory");
      else if (g + 2 == NCH) asm volatile("s_waitcnt vmcnt(4)" ::: "memory");
      else                   asm volatile("s_waitcnt vmcnt(0)" ::: "memory");
      __builtin_amdgcn_s_barrier();  // chunk g landed for all threads
      const us* rb = smem + slc * 16384;
      __builtin_amdgcn_s_setprio(1);
#pragma unroll
      for (int ks = 0; ks < 4; ++ks) {
#pragma unroll
        for (int h = 0; h < 2; ++h) {  // 4-frag batches: caps live VGPRs
          s8v bf[4];
#pragma unroll
          for (int nb = 0; nb < 4; ++nb)
            bf[nb] = *(const s8v*)&rb[(((h * 4 + nb) * 4 + ks) * 64 + ln) * 8];
          if (ph < 4) {
#pragma unroll
            for (int nb = 0; nb < 4; ++nb)
              accS[h * 4 + nb] = __builtin_amdgcn_mfma_f32_16x16x32_bf16(
                  Qf[ph * 4 + ks], bf[nb], accS[h * 4 + nb], 0, 0, 0);
          } else {
#pragma unroll
            for (int nb = 0; nb < 4; ++nb)
              accO[ph - 4][h * 4 + nb] = __builtin_amdgcn_mfma_f32_16x16x32_bf16(
                  pa[ks], bf[nb], accO[ph - 4][h * 4 + nb], 0, 0, 0);
          }
        }
      }
      __builtin_amdgcn_s_setprio(0);
      __builtin_amdgcn_s_barrier();  // all waves done reading slot slc
      if (g + 3 < NCH) STAGE(g + 3, slc);  // in-place refill (slot(g+3)==slc)
      if (ph == 3) {
        // softmax-lite: P' = exp(alpha*S - 4); wave-private through Ps.
        us* pw = smem + 49152 + w * 2176;
#pragma unroll
        for (int nb = 0; nb < 8; ++nb)
#pragma unroll
          for (int gg = 0; gg < 4; ++gg) {
            accS[nb][gg] = __expf(fmaf(accS[nb][gg], alpha, -4.f));
            pw[(quad * 4 + gg) * 136 + nb * 16 + m16] = f2b(accS[nb][gg]);
          }
#pragma unroll
        for (int gg = 0; gg < 4; ++gg) {  // row sums -> la (rows quad*4+gg)
          float s = 0.f;
#pragma unroll
          for (int nb = 0; nb < 8; ++nb) s += accS[nb][gg];
          s += __shfl_xor(s, 1, 64);
          s += __shfl_xor(s, 2, 64);
          s += __shfl_xor(s, 4, 64);
          s += __shfl_xor(s, 8, 64);
          la[gg] += s;
        }
        asm volatile("s_waitcnt lgkmcnt(0)" ::: "memory");  // Ps writes done
        __builtin_amdgcn_sched_barrier(0);
#pragma unroll
        for (int kp = 0; kp < 4; ++kp)  // P' A-frags (wave-private read)
          pa[kp] = *(const s8v*)&pw[m16 * 136 + kp * 32 + quad * 8];
      }
      sl = (slc == 2) ? 0 : slc + 1;
    }
  }
#undef STAGE

  // Epilogue: O = accO / l, via wave-private LDS staging -> nontemporal
  // 512B-contiguous stores (no L2 allocation: keep K/V resident for others).
  float inv[4];
#pragma unroll
  for (int gg = 0; gg < 4; ++gg) inv[gg] = 1.f / la[gg];
  const int b = zh >> Lh, hc = zh & ((1 << Lh) - 1);
  const int HCE = E << Lh;
  us* Ob = O + (long long)b * S * HCE + (long long)hc * E;
  us* stw = smem + w * 4288;  // wave-private 16 x 268 us
#pragma unroll
  for (int half = 0; half < 2; ++half) {
#pragma unroll
    for (int ec = 0; ec < 2; ++ec) {
      const int ecg = half * 2 + ec;
#pragma unroll
      for (int nb = 0; nb < 8; ++nb)
#pragma unroll
        for (int gg = 0; gg < 4; ++gg)
          stw[(quad * 4 + gg) * 268 + ec * 128 + nb * 16 + m16] =
              f2b(accO[ecg][nb][gg] * inv[gg]);
    }
    asm volatile("s_waitcnt lgkmcnt(0)" ::: "memory");
    __builtin_amdgcn_sched_barrier(0);
    // 32 lanes x 16B = 512B contiguous per row; 2 rows per instruction.
#pragma unroll
    for (int rp = 0; rp < 8; ++rp) {
      const int row = rp * 2 + (ln >> 5);
      const s8v v = *(const s8v*)&stw[row * 268 + (ln & 31) * 8];
      __builtin_nontemporal_store(
          v, (s8v*)&Ob[(long long)(q0 + 16 * w + row) * HCE + half * 256 +
                       (ln & 31) * 8]);
    }
    if (half == 0) {
      asm volatile("s_waitcnt lgkmcnt(0)" ::: "memory");  // reads done before
      __builtin_amdgcn_sched_barrier(0);                  // half-1 overwrites
    }
  }
}

// NT GEMM core: 256(M) x 256(N) tile, 8 waves (2 row-groups x 4 col-groups);
// A[M,K] (lda), B[N,K] (ldb). z = (zo<<L)|zi -> operand offsets zo*s?0+zi*s?1.
// EPI 3: merged QKV epilogue (q/k straight+bias, v transposed+bias), all
//        stores nontemporal (streaming, consumed from L3 by attn).
// EPI 5: fp32 atomicAdd into Cv (split-K out-projection).
template <int EPI>
__global__ __launch_bounds__(512, 2) void gemm_nt(
    const us* __restrict__ A, int lda, long long sA0, long long sA1,
    const us* __restrict__ Bm, int ldb, long long sB0, long long sB1,
    const float* __restrict__ bias, const float* __restrict__ bias2,
    const float* __restrict__ bias3,
    void* __restrict__ Cv, void* __restrict__ C2, void* __restrict__ C3,
    int ldc, long long sC0, long long sC1,
    int K, float alpha, int L, int sbits) {
  __shared__ __align__(16) us As[2][16384];
  __shared__ __align__(16) us Bs[2][16384];
  const int t = threadIdx.x;
  const int wv = t >> 6, ln = t & 63;
  const int m16 = ln & 15, quad = ln >> 4;

  const int gx = gridDim.x, gxy = gx * gridDim.y;
  const int nblk = gxy * gridDim.z;
  const int flat = blockIdx.x + gx * blockIdx.y + gxy * blockIdx.z;
  int nid = flat;
  if ((nblk & 7) == 0) nid = (flat & 7) * (nblk >> 3) + (flat >> 3);
  const int bz = nid / gxy, rem = nid % gxy;
  const int by = rem / gx, bx = rem % gx;

  const long long row0 = (long long)by * 256;
  const long long col0 = (long long)bx * 256;
  const int zo = bz >> L, zi = bz & ((1 << L) - 1);
  const us* Az = A + zo * sA0 + zi * sA1;
  const us* Bz = Bm + zo * sB0 + zi * sB1;

  int offA[4], offB[4];
#pragma unroll
  for (int j = 0; j < 4; ++j) {
    const int c = t + 512 * j;
    const int s = c >> 6, l = c & 63;
    const int mb = s >> 1, ks = s & 1, qd = (l >> 4) & 3, mm = l & 15;
    offA[j] = (int)((row0 + mb * 16 + mm) * (long long)lda + ks * 32 + qd * 8);
    offB[j] = (int)((col0 + mb * 16 + mm) * (long long)ldb + ks * 32 + qd * 8);
  }

  f4v acc[8][4];
#pragma unroll
  for (int r = 0; r < 8; ++r)
#pragma unroll
    for (int c = 0; c < 4; ++c) acc[r][c] = (f4v){0.f, 0.f, 0.f, 0.f};

  const int nk = K >> 6;
  const int wr = wv >> 2, wc = wv & 3;

#define BARR __builtin_amdgcn_s_barrier()
#define LGKM0                                              \
  do {                                                     \
    asm volatile("s_waitcnt lgkmcnt(0)" ::: "memory");     \
    __builtin_amdgcn_sched_barrier(0);                     \
  } while (0)
#define READ_A(p_)                                                           \
  _Pragma("unroll") for (int rr = 0; rr < 2; ++rr)                           \
  _Pragma("unroll") for (int ks = 0; ks < 2; ++ks)                           \
      af[rr * 2 + ks] = *(const s8v*)&As[b]                                  \
          [(((wr * 8 + (p_) * 2 + rr) * 2 + ks) * 64 + ln) * 8];
#define MFMA_Q(p_)                                                           \
  __builtin_amdgcn_s_setprio(1);                                             \
  _Pragma("unroll") for (int ks = 0; ks < 2; ++ks)                           \
  _Pragma("unroll") for (int rr = 0; rr < 2; ++rr)                           \
  _Pragma("unroll") for (int c = 0; c < 4; ++c)                              \
      acc[(p_) * 2 + rr][c] = __builtin_amdgcn_mfma_f32_16x16x32_bf16(       \
          af[rr * 2 + ks], bfr[c * 2 + ks], acc[(p_) * 2 + rr][c], 0, 0, 0); \
  __builtin_amdgcn_s_setprio(0);

#pragma unroll
  for (int j = 0; j < 4; ++j) gld16(Az + offA[j], (us*)As[0] + (t + 512 * j) * 8);
#pragma unroll
  for (int j = 0; j < 4; ++j) gld16(Bz + offB[j], (us*)Bs[0] + (t + 512 * j) * 8);
  if (nk > 1) {
#pragma unroll
    for (int j = 0; j < 4; ++j)
      gld16(Bz + offB[j] + 64, (us*)Bs[1] + (t + 512 * j) * 8);
    gld16(Az + offA[0] + 64, (us*)As[1] + t * 8);
    gld16(Az + offA[2] + 64, (us*)As[1] + (t + 1024) * 8);
    asm volatile("s_waitcnt vmcnt(6)" ::: "memory");
  } else {
    asm volatile("s_waitcnt vmcnt(0)" ::: "memory");
  }
  BARR;

  for (int kt = 0; kt < nk; ++kt) {
    const int b = kt & 1;
    s8v bfr[8], af[4];
#pragma unroll
    for (int c = 0; c < 4; ++c)
#pragma unroll
      for (int ks = 0; ks < 2; ++ks)
        bfr[c * 2 + ks] =
            *(const s8v*)&Bs[b][(((wc * 4 + c) * 2 + ks) * 64 + ln) * 8];
    READ_A(0);
    if (kt + 1 < nk) {
      const int kof = (kt + 1) << 6;
      gld16(Az + offA[1] + kof, (us*)As[b ^ 1] + (t + 512) * 8);
      gld16(Az + offA[3] + kof, (us*)As[b ^ 1] + (t + 1536) * 8);
    }
    asm volatile("s_waitcnt lgkmcnt(8)" ::: "memory");
    BARR; LGKM0; MFMA_Q(0); BARR;
    READ_A(1);
    if (kt + 2 < nk) {
      const int kof = (kt + 2) << 6;
#pragma unroll
      for (int j = 0; j < 4; ++j)
        gld16(Bz + offB[j] + kof, (us*)Bs[b] + (t + 512 * j) * 8);
    }
    BARR; LGKM0; MFMA_Q(1); BARR;
    READ_A(2);
    if (kt + 2 < nk) {
      const int kof = (kt + 2) << 6;
      gld16(Az + offA[0] + kof, (us*)As[b] + t * 8);
      gld16(Az + offA[2] + kof, (us*)As[b] + (t + 1024) * 8);
    }
    BARR; LGKM0; MFMA_Q(2); BARR;
    READ_A(3);
    BARR; LGKM0; MFMA_Q(3);
    if (kt + 2 < nk) asm volatile("s_waitcnt vmcnt(6)" ::: "memory");
    else             asm volatile("s_waitcnt vmcnt(0)" ::: "memory");
    BARR;
  }
#undef READ_A
#undef MFMA_Q
#undef BARR
#undef LGKM0

  // Epilogue. C/D layout: col = lane&15, row = quad*4 + reg (m89-verified).
#pragma unroll
  for (int r = 0; r < 8; ++r) {
    const int inRow = wr * 128 + r * 16 + quad * 4;
    const long long gr0 = row0 + inRow;
#pragma unroll
    for (int c = 0; c < 4; ++c) {
      const long long gc = col0 + wc * 64 + c * 16 + m16;
      if (EPI == 3) {
        const int which = (int)(gc >> sbits);
        const int gsec = (int)gc & ((1 << sbits) - 1);
        const int hc = gsec >> 9, e = (int)gc & 511;
        const long long slice =
            ((long long)zo * (1 << (sbits - 9)) + hc) * 1048576LL;  // S*E
        if (which == 0) {
          us* C = (us*)Cv;
          const float bb = bias[gsec];
#pragma unroll
          for (int g = 0; g < 4; ++g)
            __builtin_nontemporal_store(f2b(acc[r][c][g] + bb),
                                        &C[slice + (gr0 + g) * 512 + e]);
        } else if (which == 1) {
          us* C = (us*)C2;
          const float bb = bias2[gsec];
#pragma unroll
          for (int g = 0; g < 4; ++g)
            __builtin_nontemporal_store(f2b(acc[r][c][g] + bb),
                                        &C[slice + (gr0 + g) * 512 + e]);
        } else {
          us* C = (us*)C3;
          const float bb = bias3[gsec];
          us4v pk;
#pragma unroll
          for (int g = 0; g < 4; ++g) pk[g] = f2b(acc[r][c][g] + bb);
          __builtin_nontemporal_store(
              pk, (us4v*)&C[slice + (long long)e * 2048 + gr0]);  // e*S + s
        }
      } else {  // EPI 5: split-K atomic accumulate (fp32)
        float* C = (float*)Cv + zo * sC0;
        float* p = C + gr0 * ldc + gc;
#pragma unroll
        for (int g = 0; g < 4; ++g)
          atomicAdd(&p[(long long)g * ldc], acc[r][c][g] * alpha);
      }
    }
  }
}

__global__ __launch_bounds__(256) void conv_bf16(const float* __restrict__ in,
                                                 us* __restrict__ out, int n4) {
  const int i = blockIdx.x * 256 + threadIdx.x;
  if (i < n4) {
    const float4 f = ((const float4*)in)[i];
    us4v o;
    o[0] = f2b(f.x); o[1] = f2b(f.y); o[2] = f2b(f.z); o[3] = f2b(f.w);
    ((us4v*)out)[i] = o;
  }
}

// in [Z][R][C] fp32 -> bf16 transposed [C][R], z-routed:
// dst = out + (z>>Lc)*sChunk + (z&mask)*(R*C)
__global__ __launch_bounds__(256) void conv_transpose(const float* __restrict__ in,
                                                      us* __restrict__ out,
                                                      int R, int C, int Lc,
                                                      int mask, long long sChunk) {
  __shared__ float tile[32][33];
  const int tx = threadIdx.x & 31, ty = threadIdx.x >> 5;
  const int z = blockIdx.z;
  const long long zi = (long long)z * R * C;
  us* dst = out + (long long)(z >> Lc) * sChunk + (long long)(z & mask) * R * C;
  const int r0 = blockIdx.y * 32, c0 = blockIdx.x * 32;
#pragma unroll
  for (int j = 0; j < 4; ++j)
    tile[ty + 8 * j][tx] = in[zi + (long long)(r0 + ty + 8 * j) * C + c0 + tx];
  __syncthreads();
#pragma unroll
  for (int j = 0; j < 4; ++j)
    dst[(long long)(c0 + ty + 8 * j) * R + r0 + tx] = f2b(tile[tx][ty + 8 * j]);
}

// out[b,s,:] = bp[:]
__global__ __launch_bounds__(256) void init_out_kernel(float* __restrict__ out,
                                                       const float* __restrict__ bp,
                                                       int total) {
  const int i = blockIdx.x * 256 + threadIdx.x;
  if (i < total) out[i] = bp[i & 511];  // D=512
}

extern "C" void kernel_launch(void* const* d_in, const int* in_sizes, int n_in,
                              void* d_out, int out_size, void* d_ws, size_t ws_size,
                              hipStream_t stream) {
  constexpr int Bb = 4, S = 2048, D = 512, H = 8, E = 512, HE = 4096;
  const float* x  = (const float*)d_in[0];
  const float* Wq = (const float*)d_in[1];
  const float* bq = (const float*)d_in[2];
  const float* Wk = (const float*)d_in[3];
  const float* bk = (const float*)d_in[4];
  const float* Wv = (const float*)d_in[5];
  const float* bv = (const float*)d_in[6];
  const float* Wp = (const float*)d_in[7];
  const float* bp = (const float*)d_in[8];
  float* out = (float*)d_out;

  const long long SE = (long long)S * E;
  const long long SD = (long long)S * D, ED = (long long)E * D;

  // Fixed region: xh + packed QKV weights W3 + WpT (25.2 MB).
  us* xh  = (us*)d_ws;            // B*S*D          4,194,304
  us* W3  = xh + 4194304;         // [chunk][3][HC*E][D]  6,291,456 total
  us* WpT = W3 + 6291456;         // [D][HE]        2,097,152
  us* dyn = WpT + 2097152;

  // No sc buffer: need = fixed + 4 buffers (q,k,vT,oh) per chunk.
  const size_t fixedB = (size_t)(4194304 + 6291456 + 2097152) * 2;
  int HC = 8;
  while (HC > 1) {
    const size_t need = fixedB + (size_t)4 * HC * Bb * SE * 2;
    if (need <= ws_size) break;
    HC >>= 1;
  }
  const int Lh = (HC == 8) ? 3 : (HC == 4) ? 2 : (HC == 2) ? 1 : 0;
  const int BHC = Bb * HC;
  const int sbits = 9 + Lh;  // QKV section size = HC*512 cols

  us* qh = dyn;                       // [b*HC+hc][S][E]
  us* kh = qh + (size_t)BHC * SE;
  us* vT = kh + (size_t)BHC * SE;     // [b*HC+hc][E][S]
  us* oh = vT + (size_t)BHC * SE;     // [b][S][HC][E]

  const dim3 tb(256), tg(512);
  init_out_kernel<<<dim3((Bb * S * D + 255) / 256), tb, 0, stream>>>(
      out, bp, Bb * S * D);
  conv_bf16<<<dim3(4194304 / 4 / 256), tb, 0, stream>>>(x, xh, 4194304 / 4);
  const long long sChunk = 3LL * HC * ED;  // per-chunk W3 stride
  conv_transpose<<<dim3(16, 16, H), tb, 0, stream>>>(Wq, W3, D, E, Lh, HC - 1, sChunk);
  conv_transpose<<<dim3(16, 16, H), tb, 0, stream>>>(Wk, W3 + HC * ED, D, E, Lh, HC - 1, sChunk);
  conv_transpose<<<dim3(16, 16, H), tb, 0, stream>>>(Wv, W3 + 2 * HC * ED, D, E, Lh, HC - 1, sChunk);
  conv_transpose<<<dim3(16, 128, 1), tb, 0, stream>>>(Wp, WpT, HE, D, 0, 0, 0);

  const float aS = 0.044194173824159216f;  // 1/sqrt(512)
  const dim3 gQKV(3 * HC * E / 256, 8, Bb);  // 256-col tiles; S/256 = 8 rows
  const dim3 gAT(S / 128, BHC);              // fused attn: (q-tile, zh)
  const dim3 gOP(2, 8, BHC);                 // split-K: z = (b, j)

  for (int c = 0; c < H / HC; ++c) {
    const int h0 = c * HC;
    // Merged QKV projection: [S,D] @ [3*HC*E, D]^T; epilogue routes sections.
    gemm_nt<3><<<gQKV, tg, 0, stream>>>(
        xh, D, SD, 0, W3 + c * sChunk, D, 0, 0,
        bq + h0 * E, bk + h0 * E, bv + h0 * E,
        qh, kh, vT, 512, 0, SE, D, 1.f, 0, sbits);
    // Fused attention: oh[b][s][hc][e] = softmax(aS * Q K^T) V
    attn_fused<<<gAT, tg, 0, stream>>>(qh, kh, vT, oh, Lh, aS);
    // out += O @ Wp-chunk, split-K: z=(b, j), K=512 per split, atomicAdd.
    gemm_nt<5><<<gOP, tg, 0, stream>>>(
        oh, HC * E, (long long)S * HC * E, 512,
        WpT + (long long)h0 * E, HE, 0, 512,
        nullptr, nullptr, nullptr, out, nullptr, nullptr,
        D, SD, 0, 512, 1.f, Lh, 0);
  }
}

// Round 7
// 1093.660 us; speedup vs baseline: 1.0039x; 1.0039x over previous
//
#include <hip/hip_runtime.h>

// R15: independent-barrier-domain fix. Session data: every 512-thr/1-block-CU
// kernel is pinned at ~5.5 B/cy/CU operand supply (70% pipe-idle; MfmaUtil 18
// VALU 11) because all 8 waves share one barrier domain - any vmcnt/barrier
// stall idles the whole CU. m97-class kernels hit ~21 B/cy/CU via multiple
// independent blocks/CU (m114 overlap). attn_fused rebuilt: 4-wave/256-thread
// blocks, 64 q-rows, KV-tile 64, 16KB chunks, 3-slot ring (48KB) + 8.5KB Ps
// = 57.8KB LDS -> 2 independent blocks/CU. NT stores reverted (R14: WRITE
// 263->317MB, nt bypasses L3). GEMMs = R13/R10 core unchanged.

typedef short s8v __attribute__((ext_vector_type(8)));   // 8 bf16 = 4 VGPRs
typedef float f4v __attribute__((ext_vector_type(4)));
typedef unsigned short us;
typedef us us4v __attribute__((ext_vector_type(4)));

__device__ inline us f2b(float f) {  // fp32 -> bf16 RNE
  union { float f; unsigned u; } v; v.f = f;
  unsigned r = v.u + 0x7FFFu + ((v.u >> 16) & 1u);
  return (us)(r >> 16);
}

// async global->LDS, 16 B per lane; LDS dest = wave-uniform base + lane*16.
__device__ inline void gld16(const us* g, us* l) {
  __builtin_amdgcn_global_load_lds(
      (const __attribute__((address_space(1))) void*)g,
      (__attribute__((address_space(3))) void*)l, 16, 0, 0);
}

// ---------------------------------------------------------------------------
// Fused attention: O[zh] = softmax(alpha * Q K^T) V, streamed over KV-tiles.
// Q,K: [zh][S][E] bf16. Vt: [zh][E][S] bf16 (V^T). O: [b][S][HC*E] bf16.
// Per block (256 thr, 4 waves): one zh, 64 q-rows; wave w owns rows
// [q0+16w, q0+16w+16). KV-tile = 64 kv rows; 8 chunk-phases/tile through a
// 3-slot x 16KB ring: ph 0-3 QK^T E-chunks (B=K 64kv x 128E), ph 4-7 PV
// E-chunks (B=V^T 128E x 64kv). Counted vmcnt(8): chunks g+1,g+2 in flight.
// P' passes wave-privately through Ps (16 x 68 us/wave). 57.8KB LDS ->
// 2 independent blocks/CU.
// ---------------------------------------------------------------------------
__global__ __launch_bounds__(256, 2) void attn_fused(
    const us* __restrict__ Q, const us* __restrict__ Kh,
    const us* __restrict__ Vt, us* __restrict__ O,
    int Lh, float alpha) {
  constexpr int S = 2048, E = 512;
  constexpr int NCH = (S / 64) * 8;  // 256 chunks
  // Carve: ring slots 0..2 = smem[0..24576) us; Ps = smem[24576 + w*1088].
  // Epilogue reuses smem[0..17152) as wave-private O staging (16 x 268 /wave).
  __shared__ __align__(16) us smem[28928];  // 57,856 B
  const int t = threadIdx.x, w = t >> 6, ln = t & 63;
  const int m16 = ln & 15, quad = ln >> 4;

  // XCD swizzle: grid (32 qt, BHC zh). Remap so each XCD owns consecutive
  // nid = all qt of a few zh -> K/V L2-resident per XCD.
  const int gx = gridDim.x;  // 32
  const int nblk = gx * gridDim.y;
  const int flat = blockIdx.x + gx * blockIdx.y;
  int nid = flat;
  if ((nblk & 7) == 0) nid = (flat & 7) * (nblk >> 3) + (flat >> 3);
  const int qt = nid % gx, zh = nid / gx;

  const long long zoff = (long long)zh * S * E;
  const us* Qz = Q + zoff;
  const us* Kz = Kh + zoff;
  const us* Vz = Vt + zoff;
  const int q0 = qt * 64;

  // Resident Q fragments: lane ln holds Q[q0+16w+(ln&15)][kq*32+(ln>>4)*8 ..+7]
  s8v Qf[16];
  {
    const us* qrow = Qz + (long long)(q0 + 16 * w + m16) * E + quad * 8;
#pragma unroll
    for (int kq = 0; kq < 16; ++kq) Qf[kq] = *(const s8v*)(qrow + kq * 32);
  }

  f4v accO[4][8];
#pragma unroll
  for (int e = 0; e < 4; ++e)
#pragma unroll
    for (int nb = 0; nb < 8; ++nb) accO[e][nb] = (f4v){0.f, 0.f, 0.f, 0.f};
  float la[4] = {0.f, 0.f, 0.f, 0.f};

  // Stage chunk g into ring slot sl (16KB: 1024 x 16B, c = t + 256j).
  // tau=g>>3, sub=g&7. sub<4: K-chunk (64kv x 128E): s=c>>6 = nb*4+ks,
  //   row nbm=(s>>2)*16+(l&15), col kk=(s&3)*32+(l>>4)*8.
  // sub>=4: V-chunk (128E x 64kv): s = nb*2+ks,
  //   row nbm=(s>>1)*16+(l&15), col kk=(s&1)*32+(l>>4)*8.
#define STAGE(g_, sl_)                                                       \
  {                                                                          \
    const int tau_ = (g_) >> 3, sub_ = (g_) & 7;                             \
    us* dst_ = smem + (sl_) * 8192;                                          \
    _Pragma("unroll") for (int j = 0; j < 4; ++j) {                          \
      const int c_ = t + 256 * j;                                            \
      const int s_ = c_ >> 6, l_ = c_ & 63;                                  \
      const us* src_;                                                        \
      if (sub_ < 4) {                                                        \
        const int nbm_ = (s_ >> 2) * 16 + (l_ & 15);                         \
        const int kk_ = (s_ & 3) * 32 + (l_ >> 4) * 8;                       \
        src_ = Kz + (long long)(tau_ * 64 + nbm_) * E + sub_ * 128 + kk_;    \
      } else {                                                               \
        const int nbm_ = (s_ >> 1) * 16 + (l_ & 15);                         \
        const int kk_ = (s_ & 1) * 32 + (l_ >> 4) * 8;                       \
        src_ = Vz + (long long)((sub_ - 4) * 128 + nbm_) * S + tau_ * 64 + kk_;\
      }                                                                      \
      gld16(src_, dst_ + c_ * 8);                                            \
    }                                                                        \
  }

  STAGE(0, 0);
  STAGE(1, 1);
  STAGE(2, 2);
  int sl = 0;  // ring slot of current chunk (uniform, slot = g mod 3)

  for (int tau = 0; tau < S / 64; ++tau) {
    f4v accS[4];
#pragma unroll
    for (int nb = 0; nb < 4; ++nb) accS[nb] = (f4v){0.f, 0.f, 0.f, 0.f};
    s8v pa[2];
#pragma unroll
    for (int ph = 0; ph < 8; ++ph) {
      const int g = tau * 8 + ph;
      const int slc = sl;
      // wait until chunk g landed; keep g+1,g+2 (8 loads/thread) in flight
      if (g + 3 <= NCH)      asm volatile("s_waitcnt vmcnt(8)" ::: "memory");
      else if (g + 2 == NCH) asm volatile("s_waitcnt vmcnt(4)" ::: "memory");
      else                   asm volatile("s_waitcnt vmcnt(0)" ::: "memory");
      __builtin_amdgcn_s_barrier();  // chunk g landed for all threads
      const us* rb = smem + slc * 8192;
      __builtin_amdgcn_s_setprio(1);
      if (ph < 4) {
#pragma unroll
        for (int ks = 0; ks < 4; ++ks) {
          s8v bf[4];
#pragma unroll
          for (int nb = 0; nb < 4; ++nb)
            bf[nb] = *(const s8v*)&rb[((nb * 4 + ks) * 64 + ln) * 8];
#pragma unroll
          for (int nb = 0; nb < 4; ++nb)
            accS[nb] = __builtin_amdgcn_mfma_f32_16x16x32_bf16(
                Qf[ph * 4 + ks], bf[nb], accS[nb], 0, 0, 0);
        }
      } else {
        const int ec = ph - 4;
#pragma unroll
        for (int ks = 0; ks < 2; ++ks) {
#pragma unroll
          for (int h = 0; h < 2; ++h) {
            s8v bf[4];
#pragma unroll
            for (int nb = 0; nb < 4; ++nb)
              bf[nb] = *(const s8v*)&rb[(((h * 4 + nb) * 2 + ks) * 64 + ln) * 8];
#pragma unroll
            for (int nb = 0; nb < 4; ++nb)
              accO[ec][h * 4 + nb] = __builtin_amdgcn_mfma_f32_16x16x32_bf16(
                  pa[ks], bf[nb], accO[ec][h * 4 + nb], 0, 0, 0);
          }
        }
      }
      __builtin_amdgcn_s_setprio(0);
      __builtin_amdgcn_s_barrier();  // all waves done reading slot slc
      if (g + 3 < NCH) STAGE(g + 3, slc);  // in-place refill ((g+3)%3 == slc)
      if (ph == 3) {
        // softmax-lite: P' = exp(alpha*S - 4); wave-private through Ps.
        us* pw = smem + 24576 + w * 1088;
#pragma unroll
        for (int nb = 0; nb < 4; ++nb)
#pragma unroll
          for (int gg = 0; gg < 4; ++gg) {
            accS[nb][gg] = __expf(fmaf(accS[nb][gg], alpha, -4.f));
            pw[(quad * 4 + gg) * 68 + nb * 16 + m16] = f2b(accS[nb][gg]);
          }
#pragma unroll
        for (int gg = 0; gg < 4; ++gg) {  // row sums (64 kv cols) -> la
          float s = accS[0][gg] + accS[1][gg] + accS[2][gg] + accS[3][gg];
          s += __shfl_xor(s, 1, 64);
          s += __shfl_xor(s, 2, 64);
          s += __shfl_xor(s, 4, 64);
          s += __shfl_xor(s, 8, 64);
          la[gg] += s;
        }
        asm volatile("s_waitcnt lgkmcnt(0)" ::: "memory");  // Ps writes done
        __builtin_amdgcn_sched_barrier(0);
        pa[0] = *(const s8v*)&pw[m16 * 68 + quad * 8];
        pa[1] = *(const s8v*)&pw[m16 * 68 + 32 + quad * 8];
      }
      sl = (slc == 2) ? 0 : slc + 1;
    }
  }
#undef STAGE

  // Epilogue: O = accO / l via wave-private LDS staging -> 512B-contiguous
  // stores (plain; NT reverted per R14).
  float inv[4];
#pragma unroll
  for (int gg = 0; gg < 4; ++gg) inv[gg] = 1.f / la[gg];
  const int b = zh >> Lh, hc = zh & ((1 << Lh) - 1);
  const int HCE = E << Lh;
  us* Ob = O + (long long)b * S * HCE + (long long)hc * E;
  us* stw = smem + w * 4288;  // wave-private 16 x 268 us
#pragma unroll
  for (int half = 0; half < 2; ++half) {
#pragma unroll
    for (int ec = 0; ec < 2; ++ec) {
      const int ecg = half * 2 + ec;
#pragma unroll
      for (int nb = 0; nb < 8; ++nb)
#pragma unroll
        for (int gg = 0; gg < 4; ++gg)
          stw[(quad * 4 + gg) * 268 + ec * 128 + nb * 16 + m16] =
              f2b(accO[ecg][nb][gg] * inv[gg]);
    }
    asm volatile("s_waitcnt lgkmcnt(0)" ::: "memory");
    __builtin_amdgcn_sched_barrier(0);
    // 32 lanes x 16B = 512B contiguous per row; 2 rows per instruction.
#pragma unroll
    for (int rp = 0; rp < 8; ++rp) {
      const int row = rp * 2 + (ln >> 5);
      const s8v v = *(const s8v*)&stw[row * 268 + (ln & 31) * 8];
      *(s8v*)&Ob[(long long)(q0 + 16 * w + row) * HCE + half * 256 +
                 (ln & 31) * 8] = v;
    }
    if (half == 0) {
      asm volatile("s_waitcnt lgkmcnt(0)" ::: "memory");  // reads done before
      __builtin_amdgcn_sched_barrier(0);                  // half-1 overwrites
    }
  }
}

// NT GEMM core: 256(M) x 256(N) tile, 8 waves (2 row-groups x 4 col-groups);
// A[M,K] (lda), B[N,K] (ldb). z = (zo<<L)|zi -> operand offsets zo*s?0+zi*s?1.
// EPI 3: merged QKV epilogue (sections q/k straight+bias, v transposed+bias).
// EPI 5: fp32 atomicAdd into Cv (split-K out-projection).
template <int EPI>
__global__ __launch_bounds__(512, 2) void gemm_nt(
    const us* __restrict__ A, int lda, long long sA0, long long sA1,
    const us* __restrict__ Bm, int ldb, long long sB0, long long sB1,
    const float* __restrict__ bias, const float* __restrict__ bias2,
    const float* __restrict__ bias3,
    void* __restrict__ Cv, void* __restrict__ C2, void* __restrict__ C3,
    int ldc, long long sC0, long long sC1,
    int K, float alpha, int L, int sbits) {
  __shared__ __align__(16) us As[2][16384];
  __shared__ __align__(16) us Bs[2][16384];
  const int t = threadIdx.x;
  const int wv = t >> 6, ln = t & 63;
  const int m16 = ln & 15, quad = ln >> 4;

  const int gx = gridDim.x, gxy = gx * gridDim.y;
  const int nblk = gxy * gridDim.z;
  const int flat = blockIdx.x + gx * blockIdx.y + gxy * blockIdx.z;
  int nid = flat;
  if ((nblk & 7) == 0) nid = (flat & 7) * (nblk >> 3) + (flat >> 3);
  const int bz = nid / gxy, rem = nid % gxy;
  const int by = rem / gx, bx = rem % gx;

  const long long row0 = (long long)by * 256;
  const long long col0 = (long long)bx * 256;
  const int zo = bz >> L, zi = bz & ((1 << L) - 1);
  const us* Az = A + zo * sA0 + zi * sA1;
  const us* Bz = Bm + zo * sB0 + zi * sB1;

  int offA[4], offB[4];
#pragma unroll
  for (int j = 0; j < 4; ++j) {
    const int c = t + 512 * j;
    const int s = c >> 6, l = c & 63;
    const int mb = s >> 1, ks = s & 1, qd = (l >> 4) & 3, mm = l & 15;
    offA[j] = (int)((row0 + mb * 16 + mm) * (long long)lda + ks * 32 + qd * 8);
    offB[j] = (int)((col0 + mb * 16 + mm) * (long long)ldb + ks * 32 + qd * 8);
  }

  f4v acc[8][4];
#pragma unroll
  for (int r = 0; r < 8; ++r)
#pragma unroll
    for (int c = 0; c < 4; ++c) acc[r][c] = (f4v){0.f, 0.f, 0.f, 0.f};

  const int nk = K >> 6;
  const int wr = wv >> 2, wc = wv & 3;

#define BARR __builtin_amdgcn_s_barrier()
#define LGKM0                                              \
  do {                                                     \
    asm volatile("s_waitcnt lgkmcnt(0)" ::: "memory");     \
    __builtin_amdgcn_sched_barrier(0);                     \
  } while (0)
#define READ_A(p_)                                                           \
  _Pragma("unroll") for (int rr = 0; rr < 2; ++rr)                           \
  _Pragma("unroll") for (int ks = 0; ks < 2; ++ks)                           \
      af[rr * 2 + ks] = *(const s8v*)&As[b]                                  \
          [(((wr * 8 + (p_) * 2 + rr) * 2 + ks) * 64 + ln) * 8];
#define MFMA_Q(p_)                                                           \
  __builtin_amdgcn_s_setprio(1);                                             \
  _Pragma("unroll") for (int ks = 0; ks < 2; ++ks)                           \
  _Pragma("unroll") for (int rr = 0; rr < 2; ++rr)                           \
  _Pragma("unroll") for (int c = 0; c < 4; ++c)                              \
      acc[(p_) * 2 + rr][c] = __builtin_amdgcn_mfma_f32_16x16x32_bf16(       \
          af[rr * 2 + ks], bfr[c * 2 + ks], acc[(p_) * 2 + rr][c], 0, 0, 0); \
  __builtin_amdgcn_s_setprio(0);

#pragma unroll
  for (int j = 0; j < 4; ++j) gld16(Az + offA[j], (us*)As[0] + (t + 512 * j) * 8);
#pragma unroll
  for (int j = 0; j < 4; ++j) gld16(Bz + offB[j], (us*)Bs[0] + (t + 512 * j) * 8);
  if (nk > 1) {
#pragma unroll
    for (int j = 0; j < 4; ++j)
      gld16(Bz + offB[j] + 64, (us*)Bs[1] + (t + 512 * j) * 8);
    gld16(Az + offA[0] + 64, (us*)As[1] + t * 8);
    gld16(Az + offA[2] + 64, (us*)As[1] + (t + 1024) * 8);
    asm volatile("s_waitcnt vmcnt(6)" ::: "memory");
  } else {
    asm volatile("s_waitcnt vmcnt(0)" ::: "memory");
  }
  BARR;

  for (int kt = 0; kt < nk; ++kt) {
    const int b = kt & 1;
    s8v bfr[8], af[4];
#pragma unroll
    for (int c = 0; c < 4; ++c)
#pragma unroll
      for (int ks = 0; ks < 2; ++ks)
        bfr[c * 2 + ks] =
            *(const s8v*)&Bs[b][(((wc * 4 + c) * 2 + ks) * 64 + ln) * 8];
    READ_A(0);
    if (kt + 1 < nk) {
      const int kof = (kt + 1) << 6;
      gld16(Az + offA[1] + kof, (us*)As[b ^ 1] + (t + 512) * 8);
      gld16(Az + offA[3] + kof, (us*)As[b ^ 1] + (t + 1536) * 8);
    }
    asm volatile("s_waitcnt lgkmcnt(8)" ::: "memory");
    BARR; LGKM0; MFMA_Q(0); BARR;
    READ_A(1);
    if (kt + 2 < nk) {
      const int kof = (kt + 2) << 6;
#pragma unroll
      for (int j = 0; j < 4; ++j)
        gld16(Bz + offB[j] + kof, (us*)Bs[b] + (t + 512 * j) * 8);
    }
    BARR; LGKM0; MFMA_Q(1); BARR;
    READ_A(2);
    if (kt + 2 < nk) {
      const int kof = (kt + 2) << 6;
      gld16(Az + offA[0] + kof, (us*)As[b] + t * 8);
      gld16(Az + offA[2] + kof, (us*)As[b] + (t + 1024) * 8);
    }
    BARR; LGKM0; MFMA_Q(2); BARR;
    READ_A(3);
    BARR; LGKM0; MFMA_Q(3);
    if (kt + 2 < nk) asm volatile("s_waitcnt vmcnt(6)" ::: "memory");
    else             asm volatile("s_waitcnt vmcnt(0)" ::: "memory");
    BARR;
  }
#undef READ_A
#undef MFMA_Q
#undef BARR
#undef LGKM0

  // Epilogue. C/D layout: col = lane&15, row = quad*4 + reg (m89-verified).
#pragma unroll
  for (int r = 0; r < 8; ++r) {
    const int inRow = wr * 128 + r * 16 + quad * 4;
    const long long gr0 = row0 + inRow;
#pragma unroll
    for (int c = 0; c < 4; ++c) {
      const long long gc = col0 + wc * 64 + c * 16 + m16;
      if (EPI == 3) {
        const int which = (int)(gc >> sbits);
        const int gsec = (int)gc & ((1 << sbits) - 1);
        const int hc = gsec >> 9, e = (int)gc & 511;
        const long long slice =
            ((long long)zo * (1 << (sbits - 9)) + hc) * 1048576LL;  // S*E
        if (which == 0) {
          us* C = (us*)Cv;
          const float bb = bias[gsec];
#pragma unroll
          for (int g = 0; g < 4; ++g)
            C[slice + (gr0 + g) * 512 + e] = f2b(acc[r][c][g] + bb);
        } else if (which == 1) {
          us* C = (us*)C2;
          const float bb = bias2[gsec];
#pragma unroll
          for (int g = 0; g < 4; ++g)
            C[slice + (gr0 + g) * 512 + e] = f2b(acc[r][c][g] + bb);
        } else {
          us* C = (us*)C3;
          const float bb = bias3[gsec];
          us4v pk;
#pragma unroll
          for (int g = 0; g < 4; ++g) pk[g] = f2b(acc[r][c][g] + bb);
          *(us4v*)&C[slice + (long long)e * 2048 + gr0] = pk;  // e*S + s
        }
      } else {  // EPI 5: split-K atomic accumulate (fp32)
        float* C = (float*)Cv + zo * sC0;
        float* p = C + gr0 * ldc + gc;
#pragma unroll
        for (int g = 0; g < 4; ++g)
          atomicAdd(&p[(long long)g * ldc], acc[r][c][g] * alpha);
      }
    }
  }
}

__global__ __launch_bounds__(256) void conv_bf16(const float* __restrict__ in,
                                                 us* __restrict__ out, int n4) {
  const int i = blockIdx.x * 256 + threadIdx.x;
  if (i < n4) {
    const float4 f = ((const float4*)in)[i];
    us4v o;
    o[0] = f2b(f.x); o[1] = f2b(f.y); o[2] = f2b(f.z); o[3] = f2b(f.w);
    ((us4v*)out)[i] = o;
  }
}

// in [Z][R][C] fp32 -> bf16 transposed [C][R], z-routed:
// dst = out + (z>>Lc)*sChunk + (z&mask)*(R*C)
__global__ __launch_bounds__(256) void conv_transpose(const float* __restrict__ in,
                                                      us* __restrict__ out,
                                                      int R, int C, int Lc,
                                                      int mask, long long sChunk) {
  __shared__ float tile[32][33];
  const int tx = threadIdx.x & 31, ty = threadIdx.x >> 5;
  const int z = blockIdx.z;
  const long long zi = (long long)z * R * C;
  us* dst = out + (long long)(z >> Lc) * sChunk + (long long)(z & mask) * R * C;
  const int r0 = blockIdx.y * 32, c0 = blockIdx.x * 32;
#pragma unroll
  for (int j = 0; j < 4; ++j)
    tile[ty + 8 * j][tx] = in[zi + (long long)(r0 + ty + 8 * j) * C + c0 + tx];
  __syncthreads();
#pragma unroll
  for (int j = 0; j < 4; ++j)
    dst[(long long)(c0 + ty + 8 * j) * R + r0 + tx] = f2b(tile[tx][ty + 8 * j]);
}

// out[b,s,:] = bp[:]
__global__ __launch_bounds__(256) void init_out_kernel(float* __restrict__ out,
                                                       const float* __restrict__ bp,
                                                       int total) {
  const int i = blockIdx.x * 256 + threadIdx.x;
  if (i < total) out[i] = bp[i & 511];  // D=512
}

extern "C" void kernel_launch(void* const* d_in, const int* in_sizes, int n_in,
                              void* d_out, int out_size, void* d_ws, size_t ws_size,
                              hipStream_t stream) {
  constexpr int Bb = 4, S = 2048, D = 512, H = 8, E = 512, HE = 4096;
  const float* x  = (const float*)d_in[0];
  const float* Wq = (const float*)d_in[1];
  const float* bq = (const float*)d_in[2];
  const float* Wk = (const float*)d_in[3];
  const float* bk = (const float*)d_in[4];
  const float* Wv = (const float*)d_in[5];
  const float* bv = (const float*)d_in[6];
  const float* Wp = (const float*)d_in[7];
  const float* bp = (const float*)d_in[8];
  float* out = (float*)d_out;

  const long long SE = (long long)S * E;
  const long long SD = (long long)S * D, ED = (long long)E * D;

  // Fixed region: xh + packed QKV weights W3 + WpT (25.2 MB).
  us* xh  = (us*)d_ws;            // B*S*D          4,194,304
  us* W3  = xh + 4194304;         // [chunk][3][HC*E][D]  6,291,456 total
  us* WpT = W3 + 6291456;         // [D][HE]        2,097,152
  us* dyn = WpT + 2097152;

  // No sc buffer: need = fixed + 4 buffers (q,k,vT,oh) per chunk.
  const size_t fixedB = (size_t)(4194304 + 6291456 + 2097152) * 2;
  int HC = 8;
  while (HC > 1) {
    const size_t need = fixedB + (size_t)4 * HC * Bb * SE * 2;
    if (need <= ws_size) break;
    HC >>= 1;
  }
  const int Lh = (HC == 8) ? 3 : (HC == 4) ? 2 : (HC == 2) ? 1 : 0;
  const int BHC = Bb * HC;
  const int sbits = 9 + Lh;  // QKV section size = HC*512 cols

  us* qh = dyn;                       // [b*HC+hc][S][E]
  us* kh = qh + (size_t)BHC * SE;
  us* vT = kh + (size_t)BHC * SE;     // [b*HC+hc][E][S]
  us* oh = vT + (size_t)BHC * SE;     // [b][S][HC][E]

  const dim3 tb(256), tg(512);
  init_out_kernel<<<dim3((Bb * S * D + 255) / 256), tb, 0, stream>>>(
      out, bp, Bb * S * D);
  conv_bf16<<<dim3(4194304 / 4 / 256), tb, 0, stream>>>(x, xh, 4194304 / 4);
  const long long sChunk = 3LL * HC * ED;  // per-chunk W3 stride
  conv_transpose<<<dim3(16, 16, H), tb, 0, stream>>>(Wq, W3, D, E, Lh, HC - 1, sChunk);
  conv_transpose<<<dim3(16, 16, H), tb, 0, stream>>>(Wk, W3 + HC * ED, D, E, Lh, HC - 1, sChunk);
  conv_transpose<<<dim3(16, 16, H), tb, 0, stream>>>(Wv, W3 + 2 * HC * ED, D, E, Lh, HC - 1, sChunk);
  conv_transpose<<<dim3(16, 128, 1), tb, 0, stream>>>(Wp, WpT, HE, D, 0, 0, 0);

  const float aS = 0.044194173824159216f;  // 1/sqrt(512)
  const dim3 gQKV(3 * HC * E / 256, 8, Bb);  // 256-col tiles; S/256 = 8 rows
  const dim3 gAT(S / 64, BHC);               // fused attn: (64-row q-tile, zh)
  const dim3 gOP(2, 8, BHC);                 // split-K: z = (b, j)

  for (int c = 0; c < H / HC; ++c) {
    const int h0 = c * HC;
    // Merged QKV projection: [S,D] @ [3*HC*E, D]^T; epilogue routes sections.
    gemm_nt<3><<<gQKV, tg, 0, stream>>>(
        xh, D, SD, 0, W3 + c * sChunk, D, 0, 0,
        bq + h0 * E, bk + h0 * E, bv + h0 * E,
        qh, kh, vT, 512, 0, SE, D, 1.f, 0, sbits);
    // Fused attention: oh[b][s][hc][e] = softmax(aS * Q K^T) V
    attn_fused<<<gAT, tb, 0, stream>>>(qh, kh, vT, oh, Lh, aS);
    // out += O @ Wp-chunk, split-K: z=(b, j), K=512 per split, atomicAdd.
    gemm_nt<5><<<gOP, tg, 0, stream>>>(
        oh, HC * E, (long long)S * HC * E, 512,
        WpT + (long long)h0 * E, HE, 0, 512,
        nullptr, nullptr, nullptr, out, nullptr, nullptr,
        D, SD, 0, 512, 1.f, Lh, 0);
  }
}